// Round 7
// baseline (423.049 us; speedup 1.0000x reference)
//
#include <hip/hip_runtime.h>

// Attention: qkv = x @ W^T + b ; causal MHA ; B=4 T=2048 C=1024 H=16 D=64
// R7: flash reads pre-tiled K/V DIRECTLY global->VGPR (no LDS, no barriers,
//     no vmcnt(0) drains in the main loop). Pre-tiled layout makes every
//     fragment load perfectly coalesced (K-frag: 1KB contiguous/inst).
//     One-tile-deep K prefetch; V loads issued at tile start, consumed after
//     QK+softmax (~250 cyc of cover). LDS only for the 4-chunk cross-wave
//     reduction (16.25 KB). Waves own disjoint subtiles (fixed-m => additive).
//     cvt launches merged into one kernel. gemm unchanged from R6 (0 conflicts).
// Workspace (70 MB): xb@0 [8192][1024] | wb@16M [3072][1024]
//   qb@22M q bf16 [bh][t][d] *0.125*log2e
//   kvb@38M tiles [bh][st][ K: frag(ns,ks)*64+lane x8B16 | V: (sb*64+d)*8 ] 16KB

typedef __attribute__((ext_vector_type(8))) short short8;
typedef __attribute__((ext_vector_type(4))) short s16x4;
typedef __attribute__((ext_vector_type(4))) float f32x4;

#define AS1 __attribute__((address_space(1)))
#define AS3 __attribute__((address_space(3)))

__device__ __forceinline__ unsigned short f2bf(float f) {
  unsigned int u = __float_as_uint(f);
  u += 0x7fffu + ((u >> 16) & 1u);
  return (unsigned short)(u >> 16);
}

__device__ __forceinline__ unsigned int pack_bf16(float lo, float hi) {
  return __builtin_amdgcn_perm(__float_as_uint(hi) + 0x8000u,
                               __float_as_uint(lo) + 0x8000u, 0x07060302u);
}

// async 16B/lane global->LDS; LDS dest = wave-uniform base + lane*16
__device__ __forceinline__ void async_copy16(const unsigned short* g, unsigned short* l) {
  const AS1 unsigned char* gp = (const AS1 unsigned char*)(unsigned long long)(uintptr_t)g;
  AS3 unsigned char* lp = (AS3 unsigned char*)(unsigned int)(uintptr_t)l;
  __builtin_amdgcn_global_load_lds((const AS1 void*)gp, (AS3 void*)lp, 16, 0, 0);
}

// ---------------- fp32 -> bf16 bulk convert (x and W in one launch) --------
__global__ __launch_bounds__(256) void cvt_both(const float* __restrict__ x,
                                                const float* __restrict__ W,
                                                unsigned short* __restrict__ xb,
                                                unsigned short* __restrict__ wb) {
  int i = blockIdx.x * 256 + threadIdx.x;  // 0 .. 1441791
  const float* in;
  unsigned short* out;
  int k;
  if (i < 1048576) { in = x; out = xb; k = i; }
  else             { in = W; out = wb; k = i - 1048576; }
  const float4* p = (const float4*)in + (size_t)k * 2;
  float4 a = p[0], b = p[1];
  uint4 o;
  o.x = (unsigned)f2bf(a.x) | ((unsigned)f2bf(a.y) << 16);
  o.y = (unsigned)f2bf(a.z) | ((unsigned)f2bf(a.w) << 16);
  o.z = (unsigned)f2bf(b.x) | ((unsigned)f2bf(b.y) << 16);
  o.w = (unsigned)f2bf(b.z) | ((unsigned)f2bf(b.w) << 16);
  *(uint4*)(out + (size_t)k * 8) = o;
}

// ---------------- QKV projection GEMM (R6, 0 bank conflicts; unchanged) ----
__global__ __launch_bounds__(256) void qkv_gemm(const unsigned short* __restrict__ A,
                                                const unsigned short* __restrict__ Bw,
                                                const float* __restrict__ bias,
                                                unsigned short* __restrict__ qb,
                                                unsigned short* __restrict__ kvb) {
  const int K = 1024;
  __shared__ unsigned short As[128 * 64];
  __shared__ unsigned short Bs[128 * 64];
  int tid = threadIdx.x;
  int wave = tid >> 6, lane = tid & 63;
  int q4 = lane >> 4, l16 = lane & 15;
  int bm = blockIdx.x, bn = blockIdx.y;

  f32x4 zero = {0.f, 0.f, 0.f, 0.f};
  f32x4 acc[4][4];
#pragma unroll
  for (int i = 0; i < 4; ++i)
#pragma unroll
    for (int j = 0; j < 4; ++j) acc[i][j] = zero;

  const unsigned short* Ab = A + (size_t)(bm * 128) * K;
  const unsigned short* Bb = Bw + (size_t)(bn * 128) * K;

  const int lanec = (lane & 15) * K + (lane >> 4) * 8;
  int ac[4];
  unsigned short *lap[4], *lbp[4];
#pragma unroll
  for (int j = 0; j < 4; ++j) {
    int t4 = wave * 4 + j;
    ac[j] = ((t4 >> 3) * 64 + ((t4 >> 1) & 3) * 16) * K + (t4 & 1) * 32;
    lap[j] = As + t4 * 512;
    lbp[j] = Bs + t4 * 512;
  }

  for (int kt = 0; kt < 16; ++kt) {
    __syncthreads();
    int kbase = kt * 64;
#pragma unroll
    for (int j = 0; j < 4; ++j) {
      async_copy16(Ab + kbase + ac[j] + lanec, lap[j]);
      async_copy16(Bb + kbase + ac[j] + lanec, lbp[j]);
    }
    __syncthreads();
#pragma unroll
    for (int ks = 0; ks < 2; ++ks) {
      short8 af[4], bf[4];
#pragma unroll
      for (int i = 0; i < 4; ++i)
        af[i] = *(const short8*)(&As[((wave & 1) * 8 + i * 2 + ks) * 512 + lane * 8]);
#pragma unroll
      for (int j = 0; j < 4; ++j)
        bf[j] = *(const short8*)(&Bs[((wave >> 1) * 8 + j * 2 + ks) * 512 + lane * 8]);
#pragma unroll
      for (int i = 0; i < 4; ++i)
#pragma unroll
        for (int j = 0; j < 4; ++j)
          acc[i][j] = __builtin_amdgcn_mfma_f32_16x16x32_bf16(af[i], bf[j], acc[i][j], 0, 0, 0);
    }
  }

  const float QSCALE = 0.18033688011112042f;
  int rowbase = bm * 128 + (wave & 1) * 64;
  int colbase = bn * 128 + (wave >> 1) * 64;
#pragma unroll
  for (int j = 0; j < 4; ++j) {
    int o = colbase + j * 16 + l16;
    float bv = bias[o];
#pragma unroll
    for (int i = 0; i < 4; ++i) {
      int r0 = rowbase + i * 16 + q4 * 4;
      int b = r0 >> 11, t0 = r0 & 2047;
      if (o < 1024) {
        int h = o >> 6, d = o & 63;
#pragma unroll
        for (int r = 0; r < 4; ++r)
          qb[((((size_t)b * 16 + h) * 2048 + t0 + r) << 6) + d] =
              f2bf((acc[i][j][r] + bv) * QSCALE);
      } else if (o < 2048) {
        int o2 = o - 1024;
        int h = o2 >> 6, dd = o2 & 63;
        int st = t0 >> 6, s6 = t0 & 63;
        int ns = s6 >> 4, l16p = s6 & 15;
        int ks = dd >> 5, q4p = (dd & 31) >> 3, jj = dd & 7;
        size_t base = ((size_t)(b * 16 + h) * 32 + st) * 8192 +
                      ((ns * 2 + ks) * 64 + q4p * 16 + l16p) * 8 + jj;
#pragma unroll
        for (int r = 0; r < 4; ++r)
          kvb[base + r * 8] = f2bf(acc[i][j][r] + bv);
      } else {
        int o3 = o - 2048;
        int h = o3 >> 6, dd = o3 & 63;
        int st = t0 >> 6, sb = (t0 & 63) >> 3, j0 = t0 & 7;
        size_t base = ((size_t)(b * 16 + h) * 32 + st) * 8192 + 4096 +
                      (sb * 64 + dd) * 8 + j0;
        ushort4 pk;
        pk.x = f2bf(acc[i][j][0] + bv);
        pk.y = f2bf(acc[i][j][1] + bv);
        pk.z = f2bf(acc[i][j][2] + bv);
        pk.w = f2bf(acc[i][j][3] + bv);
        *(ushort4*)(&kvb[base]) = pk;
      }
    }
  }
}

// ---------------- Flash attention: register-direct KV, no main-loop LDS ----
// Grid (16, 64), 256 thr. Block does q-tiles bx and 31-bx (64 t each).
// Wave w processes subtiles st = w, w+4, ... <= qt reading pre-tiled KV
// straight into VGPRs (coalesced by construction). Barrier-free main loop.
__global__ __launch_bounds__(256, 2) void flash_attn(const unsigned short* __restrict__ qb,
                                                     const unsigned short* __restrict__ kvb,
                                                     float* __restrict__ out) {
  __shared__ f32x4 red[4][4][64];  // [srcwave][nd][lane], 16KB, reused per chunk
  __shared__ float lred[4][16];    // [srcwave][l16]

  const int tid = threadIdx.x;
  const int wave = tid >> 6, lane = tid & 63;
  const int q4 = lane >> 4, l16 = lane & 15;
  const int bx = blockIdx.x, bh = blockIdx.y;
  const int b = bh >> 4, h = bh & 15;

  const unsigned short* Qg = qb + (size_t)bh * (2048 * 64);
  const unsigned short* KVg = kvb + (size_t)bh * 32 * 8192;
  const s16x4 ones = {(short)0x3F80, (short)0x3F80, (short)0x3F80, (short)0x3F80};

  const int kbase = lane * 8;                                    // shorts
  const int vbase = 4096 + ((q4 >> 1) * 64 + l16) * 8 + (q4 & 1) * 4;

  for (int pass = 0; pass < 2; ++pass) {
    const int qt = pass ? 31 - bx : bx;

    short8 qf[4][2];
#pragma unroll
    for (int mt = 0; mt < 4; ++mt)
#pragma unroll
      for (int ks = 0; ks < 2; ++ks)
        qf[mt][ks] = *(const short8*)(Qg + (size_t)(qt * 64 + mt * 16 + l16) * 64 +
                                      ks * 32 + q4 * 8);

    f32x4 zero = {0.f, 0.f, 0.f, 0.f};
    f32x4 oT[4][4];  // [mt][nd]
#pragma unroll
    for (int mt = 0; mt < 4; ++mt)
#pragma unroll
      for (int nd = 0; nd < 4; ++nd) oT[mt][nd] = zero;
    f32x4 l_acc[4] = {zero, zero, zero, zero};

    int st = wave;
    if (st <= qt) {
      short8 kA[8], kB[8];
      {
        const unsigned short* tp = KVg + (size_t)st * 8192;
#pragma unroll
        for (int f = 0; f < 8; ++f) kA[f] = *(const short8*)(tp + f * 512 + kbase);
      }

      auto body = [&](short8 (&kcur)[8], short8 (&knxt)[8]) {
        const unsigned short* tc = KVg + (size_t)st * 8192;
        // V loads for current tile (consumed after QK+softmax)
        s16x4 vf[16];
#pragma unroll
        for (int ns = 0; ns < 4; ++ns)
#pragma unroll
          for (int nd = 0; nd < 4; ++nd)
            vf[ns * 4 + nd] = *(const s16x4*)(tc + vbase + ns * 1024 + nd * 128);
        // K prefetch for next tile
        int stn = (st + 4 <= qt) ? st + 4 : st;
        const unsigned short* tn = KVg + (size_t)stn * 8192;
#pragma unroll
        for (int f = 0; f < 8; ++f) knxt[f] = *(const short8*)(tn + f * 512 + kbase);

        const bool diag = (st == qt);
#pragma unroll
        for (int ns = 0; ns < 4; ++ns) {
          f32x4 sT[4];
#pragma unroll
          for (int mt = 0; mt < 4; ++mt) {
            sT[mt] = __builtin_amdgcn_mfma_f32_16x16x32_bf16(kcur[ns * 2 + 0], qf[mt][0], zero, 0, 0, 0);
            sT[mt] = __builtin_amdgcn_mfma_f32_16x16x32_bf16(kcur[ns * 2 + 1], qf[mt][1], sT[mt], 0, 0, 0);
          }
          if (diag) {
            int sgb = st * 64 + ns * 16 + q4 * 4;
#pragma unroll
            for (int mt = 0; mt < 4; ++mt) {
              int tg = qt * 64 + mt * 16 + l16;
#pragma unroll
              for (int r = 0; r < 4; ++r)
                if (sgb + r > tg) sT[mt][r] = -3.0e38f;
            }
          }
          s16x4 pf[4];
#pragma unroll
          for (int mt = 0; mt < 4; ++mt) {
            union { unsigned int u[2]; s16x4 s4; } pu;
            pu.u[0] = pack_bf16(exp2f(sT[mt][0]), exp2f(sT[mt][1]));
            pu.u[1] = pack_bf16(exp2f(sT[mt][2]), exp2f(sT[mt][3]));
            pf[mt] = pu.s4;
          }
#pragma unroll
          for (int nd = 0; nd < 4; ++nd)
#pragma unroll
            for (int mt = 0; mt < 4; ++mt)
              oT[mt][nd] = __builtin_amdgcn_mfma_f32_16x16x16bf16_1k(vf[ns * 4 + nd], pf[mt], oT[mt][nd], 0, 0, 0);
#pragma unroll
          for (int mt = 0; mt < 4; ++mt)
            l_acc[mt] = __builtin_amdgcn_mfma_f32_16x16x16bf16_1k(ones, pf[mt], l_acc[mt], 0, 0, 0);
        }
      };

      while (true) {
        body(kA, kB);
        st += 4;
        if (st > qt) break;
        body(kB, kA);
        st += 4;
        if (st > qt) break;
      }
    }

    // ---- cross-wave reduction, 4 chunks of one 16-row t-strip each ----
#pragma unroll
    for (int mt = 0; mt < 4; ++mt) {
      __syncthreads();  // prior chunk consumed / main loop done
#pragma unroll
      for (int nd = 0; nd < 4; ++nd) red[wave][nd][lane] = oT[mt][nd];
      if (q4 == 0) lred[wave][l16] = l_acc[mt][0];
      __syncthreads();
      f32x4 s = red[0][wave][lane] + red[1][wave][lane] +
                red[2][wave][lane] + red[3][wave][lane];
      float lt = lred[0][l16] + lred[1][l16] + lred[2][l16] + lred[3][l16];
      float inv = 1.0f / lt;
      int t = qt * 64 + mt * 16 + l16;
      float4 o4 = {s[0] * inv, s[1] * inv, s[2] * inv, s[3] * inv};
      *(float4*)(out + (size_t)(b * 2048 + t) * 1024 + h * 64 + wave * 16 + q4 * 4) = o4;
    }
    __syncthreads();  // protect red reuse across passes
  }
}

extern "C" void kernel_launch(void* const* d_in, const int* in_sizes, int n_in,
                              void* d_out, int out_size, void* d_ws, size_t ws_size,
                              hipStream_t stream) {
  const float* x = (const float*)d_in[0];
  const float* W = (const float*)d_in[1];
  const float* bias = (const float*)d_in[2];
  float* out = (float*)d_out;

  char* ws = (char*)d_ws;
  unsigned short* xb = (unsigned short*)(ws);
  unsigned short* wb = (unsigned short*)(ws + 16777216);
  unsigned short* qb = (unsigned short*)(ws + 23068672);
  unsigned short* kvb = (unsigned short*)(ws + 39845888);

  hipLaunchKernelGGL(cvt_both, dim3(5632), dim3(256), 0, stream, x, W, xb, wb);
  hipLaunchKernelGGL(qkv_gemm, dim3(64, 24), dim3(256), 0, stream, xb, wb, bias,
                     qb, kvb);
  hipLaunchKernelGGL(flash_attn, dim3(16, 64), dim3(256), 0, stream, qb, kvb, out);
}

// Round 8
// 249.826 us; speedup vs baseline: 1.6934x; 1.6934x over previous
//
#include <hip/hip_runtime.h>

// Attention: qkv = x @ W^T + b ; causal MHA ; B=4 T=2048 C=1024 H=16 D=64
// R8: block-shared LDS + one-tile-deep double-buffer prefetch everywhere.
//  flash: 128-thr blocks (2 waves, waves split t-rows -> no cross-wave
//    reduction), 2x16KB KV LDS double-buffer, one barrier per tile; DMA for
//    st+1 issued right after the barrier so the barrier's vmcnt(0) drains
//    tile-old (landed) loads. Fixed-m softmax (R5-verified), l via MFMA-ones,
//    lane-ordered zero-conflict layouts (R6-verified), V packed for b128 reads.
//  gemm: same double-buffer (2x(16+16)KB), pre-tiled A/W (cvt scatters into
//    fragment-tile order) -> staging is 8 contiguous DMAs, zero addr-VALU.
// Workspace (70 MB): xt@0 tiled x bf16 (16MB) | wt@16M tiled W bf16 (6MB)
//   qb@22M q bf16 [bh][t][d] *0.125*log2e (16MB) | kvb@38M KV tiles (32MB)
//   kvb tile (16KB): K units (ns*2+ks)*64+lane : K[s=ns*16+l16][k=ks*32+q4*8+j]
//                    V units 512+(ns*2+p)*64+lane : j<4 V^T[(2p)*16+l16][ns*16+q4*4+j]
//                                                   j>=4 V^T[(2p+1)*16+l16][...]

typedef __attribute__((ext_vector_type(8))) short short8;
typedef __attribute__((ext_vector_type(4))) short s16x4;
typedef __attribute__((ext_vector_type(4))) float f32x4;

#define AS1 __attribute__((address_space(1)))
#define AS3 __attribute__((address_space(3)))

__device__ __forceinline__ unsigned short f2bf(float f) {
  unsigned int u = __float_as_uint(f);
  u += 0x7fffu + ((u >> 16) & 1u);
  return (unsigned short)(u >> 16);
}

__device__ __forceinline__ unsigned int pack_bf16(float lo, float hi) {
  return __builtin_amdgcn_perm(__float_as_uint(hi) + 0x8000u,
                               __float_as_uint(lo) + 0x8000u, 0x07060302u);
}

// async 16B/lane global->LDS; LDS dest = wave-uniform base + lane*16
__device__ __forceinline__ void async_copy16(const unsigned short* g, unsigned short* l) {
  const AS1 unsigned char* gp = (const AS1 unsigned char*)(unsigned long long)(uintptr_t)g;
  AS3 unsigned char* lp = (AS3 unsigned char*)(unsigned int)(uintptr_t)l;
  __builtin_amdgcn_global_load_lds((const AS1 void*)gp, (AS3 void*)lp, 16, 0, 0);
}

// ---------------- fp32 -> bf16 convert + fragment-tile scatter --------------
// Tiled layout (A and W identical): ((bt*16 + kt)*16 + frag)*512 + (q4*16+l16)*8
// frag = half*8 + i*2 + ks ; holds M[bt*128 + half*64 + i*16 + l16][kt*64 + ks*32 + q4*8 + j]
__global__ __launch_bounds__(256) void cvt_both(const float* __restrict__ x,
                                                const float* __restrict__ W,
                                                unsigned short* __restrict__ xt,
                                                unsigned short* __restrict__ wt) {
  int i = blockIdx.x * 256 + threadIdx.x;  // 0 .. 1441791 (8 floats each)
  const float* in;
  unsigned short* out;
  int k;
  if (i < 1048576) { in = x; out = xt; k = i; }
  else             { in = W; out = wt; k = i - 1048576; }
  int row = k >> 7, colg = k & 127;
  int bt = row >> 7, r7 = row & 127;
  int frag = (r7 >> 6) * 8 + ((r7 >> 4) & 3) * 2 + ((colg >> 2) & 1);
  int kt = colg >> 3;
  int dst = ((bt * 16 + kt) * 16 + frag) * 512 + ((colg & 3) * 16 + (row & 15)) * 8;
  const float4* p = (const float4*)in + (size_t)k * 2;
  float4 a = p[0], b = p[1];
  uint4 o;
  o.x = (unsigned)f2bf(a.x) | ((unsigned)f2bf(a.y) << 16);
  o.y = (unsigned)f2bf(a.z) | ((unsigned)f2bf(a.w) << 16);
  o.z = (unsigned)f2bf(b.x) | ((unsigned)f2bf(b.y) << 16);
  o.w = (unsigned)f2bf(b.z) | ((unsigned)f2bf(b.w) << 16);
  *(uint4*)(out + dst) = o;
}

// ---------------- QKV GEMM: double-buffered, pre-tiled staging --------------
// 128x128 tile, BK=64, 4 waves 2x2. LDS 2 x (16KB A + 16KB B) = 64KB.
__global__ __launch_bounds__(256) void qkv_gemm(const unsigned short* __restrict__ xt,
                                                const unsigned short* __restrict__ wt,
                                                const float* __restrict__ bias,
                                                unsigned short* __restrict__ qb,
                                                unsigned short* __restrict__ kvb) {
  __shared__ unsigned short As[2][8192];
  __shared__ unsigned short Bs[2][8192];
  int tid = threadIdx.x;
  int wave = tid >> 6, lane = tid & 63;
  int q4 = lane >> 4, l16 = lane & 15;
  int bm = blockIdx.x, bn = blockIdx.y;

  f32x4 zero = {0.f, 0.f, 0.f, 0.f};
  f32x4 acc[4][4];
#pragma unroll
  for (int i = 0; i < 4; ++i)
#pragma unroll
    for (int j = 0; j < 4; ++j) acc[i][j] = zero;

  const unsigned short* Abase = xt + (size_t)bm * 16 * 8192;
  const unsigned short* Bbase = wt + (size_t)bn * 16 * 8192;

  auto stageAB = [&](int d, int kt) {
    const unsigned short* ga = Abase + (size_t)kt * 8192;
    const unsigned short* gb = Bbase + (size_t)kt * 8192;
#pragma unroll
    for (int i2 = 0; i2 < 4; ++i2) {
      int u = i2 * 256 + wave * 64;
      async_copy16(ga + (u + lane) * 8, &As[d][u * 8]);
      async_copy16(gb + (u + lane) * 8, &Bs[d][u * 8]);
    }
  };

  stageAB(0, 0);
  for (int kt = 0; kt < 16; ++kt) {
    __syncthreads();  // drains buf[kt&1]'s DMAs (tile-old); protects buf[kt+1&1]
    if (kt < 15) stageAB((kt + 1) & 1, kt + 1);
    const unsigned short* Ac = As[kt & 1];
    const unsigned short* Bc = Bs[kt & 1];
#pragma unroll
    for (int ks = 0; ks < 2; ++ks) {
      short8 af[4], bf[4];
#pragma unroll
      for (int i = 0; i < 4; ++i)
        af[i] = *(const short8*)(Ac + ((wave & 1) * 8 + i * 2 + ks) * 512 + lane * 8);
#pragma unroll
      for (int j = 0; j < 4; ++j)
        bf[j] = *(const short8*)(Bc + ((wave >> 1) * 8 + j * 2 + ks) * 512 + lane * 8);
#pragma unroll
      for (int i = 0; i < 4; ++i)
#pragma unroll
        for (int j = 0; j < 4; ++j)
          acc[i][j] = __builtin_amdgcn_mfma_f32_16x16x32_bf16(af[i], bf[j], acc[i][j], 0, 0, 0);
    }
  }

  // epilogue: +bias; q *0.125*log2e -> qb[bh][t][d]; k,v -> pre-tiled kvb
  const float QSCALE = 0.18033688011112042f;
  int rowbase = bm * 128 + (wave & 1) * 64;
  int colbase = bn * 128 + (wave >> 1) * 64;
#pragma unroll
  for (int j = 0; j < 4; ++j) {
    int o = colbase + j * 16 + l16;
    float bv = bias[o];
#pragma unroll
    for (int i = 0; i < 4; ++i) {
      int r0 = rowbase + i * 16 + q4 * 4;
      int b = r0 >> 11, t0 = r0 & 2047;
      if (o < 1024) {
        int h = o >> 6, d = o & 63;
#pragma unroll
        for (int r = 0; r < 4; ++r)
          qb[((((size_t)b * 16 + h) * 2048 + t0 + r) << 6) + d] =
              f2bf((acc[i][j][r] + bv) * QSCALE);
      } else if (o < 2048) {
        int o2 = o - 1024;
        int h = o2 >> 6, dd = o2 & 63;
        int st = t0 >> 6, s6 = t0 & 63;
        int ns = s6 >> 4, l16p = s6 & 15;
        int ks = dd >> 5, q4p = (dd & 31) >> 3, jj = dd & 7;
        size_t base = ((size_t)(b * 16 + h) * 32 + st) * 8192 +
                      ((ns * 2 + ks) * 64 + q4p * 16 + l16p) * 8 + jj;
#pragma unroll
        for (int r = 0; r < 4; ++r)
          kvb[base + r * 8] = f2bf(acc[i][j][r] + bv);
      } else {
        int o3 = o - 2048;
        int h = o3 >> 6, dd = o3 & 63;       // dd = d
        int st = t0 >> 6, s6 = t0 & 63;
        int ns = s6 >> 4, q4p = (s6 >> 2) & 3;  // s = ns*16 + q4p*4 + r
        int p = dd >> 5, halfd = (dd >> 4) & 1, l16p = dd & 15;
        size_t base = ((size_t)(b * 16 + h) * 32 + st) * 8192 + 4096 +
                      ((ns * 2 + p) * 64 + q4p * 16 + l16p) * 8 + halfd * 4;
        ushort4 pk;
        pk.x = f2bf(acc[i][j][0] + bv);
        pk.y = f2bf(acc[i][j][1] + bv);
        pk.z = f2bf(acc[i][j][2] + bv);
        pk.w = f2bf(acc[i][j][3] + bv);
        *(ushort4*)(&kvb[base]) = pk;
      }
    }
  }
}

// ---------------- Flash attention: 2-wave blocks, double-buffered KV --------
// Grid (16, 64), 128 thr. Block does q-tiles bx and 31-bx (64 t each);
// wave w owns rows w*32..w*32+31 (no cross-wave reduction). K-subtile = 64.
__global__ __launch_bounds__(128, 2) void flash_attn(const unsigned short* __restrict__ qb,
                                                     const unsigned short* __restrict__ kvb,
                                                     float* __restrict__ out) {
  __shared__ unsigned short buf[2][8192];  // 2 x 16KB KV tiles

  const int tid = threadIdx.x;
  const int wave = tid >> 6, lane = tid & 63;
  const int q4 = lane >> 4, l16 = lane & 15;
  const int bx = blockIdx.x, bh = blockIdx.y;
  const int b = bh >> 4, h = bh & 15;

  const unsigned short* Qg = qb + (size_t)bh * (2048 * 64);
  const unsigned short* KVg = kvb + (size_t)bh * 32 * 8192;
  const s16x4 ones = {(short)0x3F80, (short)0x3F80, (short)0x3F80, (short)0x3F80};

  auto stage = [&](int d, int st) {
    const unsigned short* tp = KVg + (size_t)st * 8192;
#pragma unroll
    for (int i2 = 0; i2 < 8; ++i2) {
      int u = i2 * 128 + wave * 64;
      async_copy16(tp + (u + lane) * 8, &buf[d][u * 8]);
    }
  };

  for (int pass = 0; pass < 2; ++pass) {
    const int qt = pass ? 31 - bx : bx;
    const int t0w = qt * 64 + wave * 32;

    short8 qf[2][2];
#pragma unroll
    for (int mt = 0; mt < 2; ++mt)
#pragma unroll
      for (int ks = 0; ks < 2; ++ks)
        qf[mt][ks] = *(const short8*)(Qg + (size_t)(t0w + mt * 16 + l16) * 64 +
                                      ks * 32 + q4 * 8);

    f32x4 zero = {0.f, 0.f, 0.f, 0.f};
    f32x4 oT[2][4];
#pragma unroll
    for (int mt = 0; mt < 2; ++mt)
#pragma unroll
      for (int nd = 0; nd < 4; ++nd) oT[mt][nd] = zero;
    f32x4 l_acc[2] = {zero, zero};

    __syncthreads();  // prior pass's reads of buf0 done before restaging
    stage(0, 0);
    for (int st = 0; st <= qt; ++st) {
      __syncthreads();  // drains buf[st&1] DMAs (tile-old); guards overwrite
      if (st < qt) stage((st + 1) & 1, st + 1);
      const unsigned short* cur = buf[st & 1];

      // S^T = K Q^T : sT[mt][ns][r] = S[s=st*64+ns*16+q4*4+r][t=t0w+mt*16+l16]
      f32x4 sT[2][4];
#pragma unroll
      for (int ns = 0; ns < 4; ++ns) {
        short8 kf0 = *(const short8*)(cur + (ns * 2 + 0) * 512 + lane * 8);
        short8 kf1 = *(const short8*)(cur + (ns * 2 + 1) * 512 + lane * 8);
#pragma unroll
        for (int mt = 0; mt < 2; ++mt) {
          sT[mt][ns] = __builtin_amdgcn_mfma_f32_16x16x32_bf16(kf0, qf[mt][0], zero, 0, 0, 0);
          sT[mt][ns] = __builtin_amdgcn_mfma_f32_16x16x32_bf16(kf1, qf[mt][1], sT[mt][ns], 0, 0, 0);
        }
      }

      // causal mask on the diagonal tile; exp2(-3e38)=0
      if (st == qt) {
#pragma unroll
        for (int mt = 0; mt < 2; ++mt) {
          int tg = t0w + mt * 16 + l16;
#pragma unroll
          for (int ns = 0; ns < 4; ++ns) {
            int sgb = st * 64 + ns * 16 + q4 * 4;
#pragma unroll
            for (int r = 0; r < 4; ++r)
              if (sgb + r > tg) sT[mt][ns][r] = -3.0e38f;
          }
        }
      }

      // fixed-m: P = exp2(s); PV + l in the matrix pipe
#pragma unroll
      for (int ns = 0; ns < 4; ++ns) {
        s16x4 pf[2];
#pragma unroll
        for (int mt = 0; mt < 2; ++mt) {
          union { unsigned int u[2]; s16x4 s4; } pu;
          pu.u[0] = pack_bf16(exp2f(sT[mt][ns][0]), exp2f(sT[mt][ns][1]));
          pu.u[1] = pack_bf16(exp2f(sT[mt][ns][2]), exp2f(sT[mt][ns][3]));
          pf[mt] = pu.s4;
        }
#pragma unroll
        for (int p = 0; p < 2; ++p) {
          short8 v8 = *(const short8*)(cur + 4096 + ((ns * 2 + p) * 64 + lane) * 8);
          s16x4 vlo = __builtin_shufflevector(v8, v8, 0, 1, 2, 3);
          s16x4 vhi = __builtin_shufflevector(v8, v8, 4, 5, 6, 7);
#pragma unroll
          for (int mt = 0; mt < 2; ++mt) {
            oT[mt][2 * p] = __builtin_amdgcn_mfma_f32_16x16x16bf16_1k(vlo, pf[mt], oT[mt][2 * p], 0, 0, 0);
            oT[mt][2 * p + 1] = __builtin_amdgcn_mfma_f32_16x16x16bf16_1k(vhi, pf[mt], oT[mt][2 * p + 1], 0, 0, 0);
          }
        }
#pragma unroll
        for (int mt = 0; mt < 2; ++mt)
          l_acc[mt] = __builtin_amdgcn_mfma_f32_16x16x16bf16_1k(ones, pf[mt], l_acc[mt], 0, 0, 0);
      }
    }

    // epilogue: out[b][t=t0w+mt*16+l16][h*64 + nd*16 + q4*4 + r] = oT/l
#pragma unroll
    for (int mt = 0; mt < 2; ++mt) {
      float inv = 1.0f / l_acc[mt][0];
      int t = t0w + mt * 16 + l16;
      float* op = out + (size_t)(b * 2048 + t) * 1024 + h * 64 + q4 * 4;
#pragma unroll
      for (int nd = 0; nd < 4; ++nd) {
        float4 o4 = {oT[mt][nd][0] * inv, oT[mt][nd][1] * inv,
                     oT[mt][nd][2] * inv, oT[mt][nd][3] * inv};
        *(float4*)(op + nd * 16) = o4;
      }
    }
  }
}

extern "C" void kernel_launch(void* const* d_in, const int* in_sizes, int n_in,
                              void* d_out, int out_size, void* d_ws, size_t ws_size,
                              hipStream_t stream) {
  const float* x = (const float*)d_in[0];
  const float* W = (const float*)d_in[1];
  const float* bias = (const float*)d_in[2];
  float* out = (float*)d_out;

  char* ws = (char*)d_ws;
  unsigned short* xt = (unsigned short*)(ws);
  unsigned short* wt = (unsigned short*)(ws + 16777216);
  unsigned short* qb = (unsigned short*)(ws + 23068672);
  unsigned short* kvb = (unsigned short*)(ws + 39845888);

  hipLaunchKernelGGL(cvt_both, dim3(5632), dim3(256), 0, stream, x, W, xt, wt);
  hipLaunchKernelGGL(qkv_gemm, dim3(64, 24), dim3(256), 0, stream, xt, wt, bias,
                     qb, kvb);
  hipLaunchKernelGGL(flash_attn, dim3(16, 64), dim3(128), 0, stream, qb, kvb, out);
}

// Round 9
// 211.626 us; speedup vs baseline: 1.9990x; 1.1805x over previous
//
#include <hip/hip_runtime.h>

// Attention: qkv = x @ W^T + b ; causal MHA ; B=4 T=2048 C=1024 H=16 D=64
// R9 (flash-only changes; gemm/cvt frozen from R8):
//  - exp2 via __builtin_amdgcn_exp2f (raw v_exp_f32, 1 ULP). Plain exp2f()
//    without fast-math lowers to the OCML precise path (~18 inst) — that was
//    the unexplained 3x VALU excess in R8's census (46% VALUBusy).
//  - XCD-aware block remap: block n -> xcd=n&7, bh=xcd*8+((n>>3)&7), bx=n>>6.
//    All 16 blocks of one head share an XCD; per-XCD KV set = 4MB ~= L2.
//    R8 spread each head across all 8 XCDs -> 257MB HBM fetch (capacity
//    thrash); compulsory is ~48MB.
//  - __launch_bounds__(128,4): allow 5 blocks/CU (LDS-capped) vs 4.
// Structure (verified R8): 2-wave blocks split t-rows, 2x16KB KV LDS double
// buffer, one barrier/tile with DMA issued tile-early, fixed-m softmax,
// l via MFMA-ones, lane-ordered zero-conflict pre-tiled layouts.
// Workspace (70 MB): xt@0 tiled x bf16 | wt@16M tiled W | qb@22M q bf16
//   [bh][t][d] *0.125*log2e | kvb@38M KV tiles 16KB/tile.

typedef __attribute__((ext_vector_type(8))) short short8;
typedef __attribute__((ext_vector_type(4))) short s16x4;
typedef __attribute__((ext_vector_type(4))) float f32x4;

#define AS1 __attribute__((address_space(1)))
#define AS3 __attribute__((address_space(3)))

__device__ __forceinline__ unsigned short f2bf(float f) {
  unsigned int u = __float_as_uint(f);
  u += 0x7fffu + ((u >> 16) & 1u);
  return (unsigned short)(u >> 16);
}

__device__ __forceinline__ unsigned int pack_bf16(float lo, float hi) {
  return __builtin_amdgcn_perm(__float_as_uint(hi) + 0x8000u,
                               __float_as_uint(lo) + 0x8000u, 0x07060302u);
}

// async 16B/lane global->LDS; LDS dest = wave-uniform base + lane*16
__device__ __forceinline__ void async_copy16(const unsigned short* g, unsigned short* l) {
  const AS1 unsigned char* gp = (const AS1 unsigned char*)(unsigned long long)(uintptr_t)g;
  AS3 unsigned char* lp = (AS3 unsigned char*)(unsigned int)(uintptr_t)l;
  __builtin_amdgcn_global_load_lds((const AS1 void*)gp, (AS3 void*)lp, 16, 0, 0);
}

// ---------------- fp32 -> bf16 convert + fragment-tile scatter (R8) ---------
__global__ __launch_bounds__(256) void cvt_both(const float* __restrict__ x,
                                                const float* __restrict__ W,
                                                unsigned short* __restrict__ xt,
                                                unsigned short* __restrict__ wt) {
  int i = blockIdx.x * 256 + threadIdx.x;
  const float* in;
  unsigned short* out;
  int k;
  if (i < 1048576) { in = x; out = xt; k = i; }
  else             { in = W; out = wt; k = i - 1048576; }
  int row = k >> 7, colg = k & 127;
  int bt = row >> 7, r7 = row & 127;
  int frag = (r7 >> 6) * 8 + ((r7 >> 4) & 3) * 2 + ((colg >> 2) & 1);
  int kt = colg >> 3;
  int dst = ((bt * 16 + kt) * 16 + frag) * 512 + ((colg & 3) * 16 + (row & 15)) * 8;
  const float4* p = (const float4*)in + (size_t)k * 2;
  float4 a = p[0], b = p[1];
  uint4 o;
  o.x = (unsigned)f2bf(a.x) | ((unsigned)f2bf(a.y) << 16);
  o.y = (unsigned)f2bf(a.z) | ((unsigned)f2bf(a.w) << 16);
  o.z = (unsigned)f2bf(b.x) | ((unsigned)f2bf(b.y) << 16);
  o.w = (unsigned)f2bf(b.z) | ((unsigned)f2bf(b.w) << 16);
  *(uint4*)(out + dst) = o;
}

// ---------------- QKV GEMM: double-buffered, pre-tiled staging (R8) ---------
__global__ __launch_bounds__(256) void qkv_gemm(const unsigned short* __restrict__ xt,
                                                const unsigned short* __restrict__ wt,
                                                const float* __restrict__ bias,
                                                unsigned short* __restrict__ qb,
                                                unsigned short* __restrict__ kvb) {
  __shared__ unsigned short As[2][8192];
  __shared__ unsigned short Bs[2][8192];
  int tid = threadIdx.x;
  int wave = tid >> 6, lane = tid & 63;
  int q4 = lane >> 4, l16 = lane & 15;
  int bm = blockIdx.x, bn = blockIdx.y;

  f32x4 zero = {0.f, 0.f, 0.f, 0.f};
  f32x4 acc[4][4];
#pragma unroll
  for (int i = 0; i < 4; ++i)
#pragma unroll
    for (int j = 0; j < 4; ++j) acc[i][j] = zero;

  const unsigned short* Abase = xt + (size_t)bm * 16 * 8192;
  const unsigned short* Bbase = wt + (size_t)bn * 16 * 8192;

  auto stageAB = [&](int d, int kt) {
    const unsigned short* ga = Abase + (size_t)kt * 8192;
    const unsigned short* gb = Bbase + (size_t)kt * 8192;
#pragma unroll
    for (int i2 = 0; i2 < 4; ++i2) {
      int u = i2 * 256 + wave * 64;
      async_copy16(ga + (u + lane) * 8, &As[d][u * 8]);
      async_copy16(gb + (u + lane) * 8, &Bs[d][u * 8]);
    }
  };

  stageAB(0, 0);
  for (int kt = 0; kt < 16; ++kt) {
    __syncthreads();
    if (kt < 15) stageAB((kt + 1) & 1, kt + 1);
    const unsigned short* Ac = As[kt & 1];
    const unsigned short* Bc = Bs[kt & 1];
#pragma unroll
    for (int ks = 0; ks < 2; ++ks) {
      short8 af[4], bf[4];
#pragma unroll
      for (int i = 0; i < 4; ++i)
        af[i] = *(const short8*)(Ac + ((wave & 1) * 8 + i * 2 + ks) * 512 + lane * 8);
#pragma unroll
      for (int j = 0; j < 4; ++j)
        bf[j] = *(const short8*)(Bc + ((wave >> 1) * 8 + j * 2 + ks) * 512 + lane * 8);
#pragma unroll
      for (int i = 0; i < 4; ++i)
#pragma unroll
        for (int j = 0; j < 4; ++j)
          acc[i][j] = __builtin_amdgcn_mfma_f32_16x16x32_bf16(af[i], bf[j], acc[i][j], 0, 0, 0);
    }
  }

  const float QSCALE = 0.18033688011112042f;
  int rowbase = bm * 128 + (wave & 1) * 64;
  int colbase = bn * 128 + (wave >> 1) * 64;
#pragma unroll
  for (int j = 0; j < 4; ++j) {
    int o = colbase + j * 16 + l16;
    float bv = bias[o];
#pragma unroll
    for (int i = 0; i < 4; ++i) {
      int r0 = rowbase + i * 16 + q4 * 4;
      int b = r0 >> 11, t0 = r0 & 2047;
      if (o < 1024) {
        int h = o >> 6, d = o & 63;
#pragma unroll
        for (int r = 0; r < 4; ++r)
          qb[((((size_t)b * 16 + h) * 2048 + t0 + r) << 6) + d] =
              f2bf((acc[i][j][r] + bv) * QSCALE);
      } else if (o < 2048) {
        int o2 = o - 1024;
        int h = o2 >> 6, dd = o2 & 63;
        int st = t0 >> 6, s6 = t0 & 63;
        int ns = s6 >> 4, l16p = s6 & 15;
        int ks = dd >> 5, q4p = (dd & 31) >> 3, jj = dd & 7;
        size_t base = ((size_t)(b * 16 + h) * 32 + st) * 8192 +
                      ((ns * 2 + ks) * 64 + q4p * 16 + l16p) * 8 + jj;
#pragma unroll
        for (int r = 0; r < 4; ++r)
          kvb[base + r * 8] = f2bf(acc[i][j][r] + bv);
      } else {
        int o3 = o - 2048;
        int h = o3 >> 6, dd = o3 & 63;
        int st = t0 >> 6, s6 = t0 & 63;
        int ns = s6 >> 4, q4p = (s6 >> 2) & 3;
        int p = dd >> 5, halfd = (dd >> 4) & 1, l16p = dd & 15;
        size_t base = ((size_t)(b * 16 + h) * 32 + st) * 8192 + 4096 +
                      ((ns * 2 + p) * 64 + q4p * 16 + l16p) * 8 + halfd * 4;
        ushort4 pk;
        pk.x = f2bf(acc[i][j][0] + bv);
        pk.y = f2bf(acc[i][j][1] + bv);
        pk.z = f2bf(acc[i][j][2] + bv);
        pk.w = f2bf(acc[i][j][3] + bv);
        *(ushort4*)(&kvb[base]) = pk;
      }
    }
  }
}

// ---------------- Flash attention: XCD-local heads, raw exp2 ----------------
// Grid 1024 (1-D), 128 thr. n -> xcd=n&7, bh=xcd*8+((n>>3)&7), bx=n>>6.
// Block does q-tiles bx and 31-bx; wave w owns t-rows w*32..+31.
__global__ __launch_bounds__(128, 4) void flash_attn(const unsigned short* __restrict__ qb,
                                                     const unsigned short* __restrict__ kvb,
                                                     float* __restrict__ out) {
  __shared__ unsigned short buf[2][8192];

  const int tid = threadIdx.x;
  const int wave = tid >> 6, lane = tid & 63;
  const int q4 = lane >> 4, l16 = lane & 15;
  const int n = blockIdx.x;
  const int bh = (n & 7) * 8 + ((n >> 3) & 7);
  const int bx = n >> 6;
  const int b = bh >> 4, h = bh & 15;

  const unsigned short* Qg = qb + (size_t)bh * (2048 * 64);
  const unsigned short* KVg = kvb + (size_t)bh * 32 * 8192;
  const s16x4 ones = {(short)0x3F80, (short)0x3F80, (short)0x3F80, (short)0x3F80};

  auto stage = [&](int d, int st) {
    const unsigned short* tp = KVg + (size_t)st * 8192;
#pragma unroll
    for (int i2 = 0; i2 < 8; ++i2) {
      int u = i2 * 128 + wave * 64;
      async_copy16(tp + (u + lane) * 8, &buf[d][u * 8]);
    }
  };

  for (int pass = 0; pass < 2; ++pass) {
    const int qt = pass ? 31 - bx : bx;
    const int t0w = qt * 64 + wave * 32;

    short8 qf[2][2];
#pragma unroll
    for (int mt = 0; mt < 2; ++mt)
#pragma unroll
      for (int ks = 0; ks < 2; ++ks)
        qf[mt][ks] = *(const short8*)(Qg + (size_t)(t0w + mt * 16 + l16) * 64 +
                                      ks * 32 + q4 * 8);

    f32x4 zero = {0.f, 0.f, 0.f, 0.f};
    f32x4 oT[2][4];
#pragma unroll
    for (int mt = 0; mt < 2; ++mt)
#pragma unroll
      for (int nd = 0; nd < 4; ++nd) oT[mt][nd] = zero;
    f32x4 l_acc[2] = {zero, zero};

    __syncthreads();  // prior pass's reads done before restaging buf0
    stage(0, 0);
    for (int st = 0; st <= qt; ++st) {
      __syncthreads();  // drains buf[st&1] DMAs (issued a tile ago)
      if (st < qt) stage((st + 1) & 1, st + 1);
      const unsigned short* cur = buf[st & 1];

      f32x4 sT[2][4];
#pragma unroll
      for (int ns = 0; ns < 4; ++ns) {
        short8 kf0 = *(const short8*)(cur + (ns * 2 + 0) * 512 + lane * 8);
        short8 kf1 = *(const short8*)(cur + (ns * 2 + 1) * 512 + lane * 8);
#pragma unroll
        for (int mt = 0; mt < 2; ++mt) {
          sT[mt][ns] = __builtin_amdgcn_mfma_f32_16x16x32_bf16(kf0, qf[mt][0], zero, 0, 0, 0);
          sT[mt][ns] = __builtin_amdgcn_mfma_f32_16x16x32_bf16(kf1, qf[mt][1], sT[mt][ns], 0, 0, 0);
        }
      }

      if (st == qt) {  // diagonal: mask s > t; exp2(-3e38) = 0
#pragma unroll
        for (int mt = 0; mt < 2; ++mt) {
          int tg = t0w + mt * 16 + l16;
#pragma unroll
          for (int ns = 0; ns < 4; ++ns) {
            int sgb = st * 64 + ns * 16 + q4 * 4;
#pragma unroll
            for (int r = 0; r < 4; ++r)
              if (sgb + r > tg) sT[mt][ns][r] = -3.0e38f;
          }
        }
      }

      // fixed-m: P = exp2(s) via raw v_exp_f32 (1 ULP); PV + l in matrix pipe
#pragma unroll
      for (int ns = 0; ns < 4; ++ns) {
        s16x4 pf[2];
#pragma unroll
        for (int mt = 0; mt < 2; ++mt) {
          union { unsigned int u[2]; s16x4 s4; } pu;
          pu.u[0] = pack_bf16(__builtin_amdgcn_exp2f(sT[mt][ns][0]),
                              __builtin_amdgcn_exp2f(sT[mt][ns][1]));
          pu.u[1] = pack_bf16(__builtin_amdgcn_exp2f(sT[mt][ns][2]),
                              __builtin_amdgcn_exp2f(sT[mt][ns][3]));
          pf[mt] = pu.s4;
        }
#pragma unroll
        for (int p = 0; p < 2; ++p) {
          short8 v8 = *(const short8*)(cur + 4096 + ((ns * 2 + p) * 64 + lane) * 8);
          s16x4 vlo = __builtin_shufflevector(v8, v8, 0, 1, 2, 3);
          s16x4 vhi = __builtin_shufflevector(v8, v8, 4, 5, 6, 7);
#pragma unroll
          for (int mt = 0; mt < 2; ++mt) {
            oT[mt][2 * p] = __builtin_amdgcn_mfma_f32_16x16x16bf16_1k(vlo, pf[mt], oT[mt][2 * p], 0, 0, 0);
            oT[mt][2 * p + 1] = __builtin_amdgcn_mfma_f32_16x16x16bf16_1k(vhi, pf[mt], oT[mt][2 * p + 1], 0, 0, 0);
          }
        }
#pragma unroll
        for (int mt = 0; mt < 2; ++mt)
          l_acc[mt] = __builtin_amdgcn_mfma_f32_16x16x16bf16_1k(ones, pf[mt], l_acc[mt], 0, 0, 0);
      }
    }

#pragma unroll
    for (int mt = 0; mt < 2; ++mt) {
      float inv = 1.0f / l_acc[mt][0];
      int t = t0w + mt * 16 + l16;
      float* op = out + (size_t)(b * 2048 + t) * 1024 + h * 64 + q4 * 4;
#pragma unroll
      for (int nd = 0; nd < 4; ++nd) {
        float4 o4 = {oT[mt][nd][0] * inv, oT[mt][nd][1] * inv,
                     oT[mt][nd][2] * inv, oT[mt][nd][3] * inv};
        *(float4*)(op + nd * 16) = o4;
      }
    }
  }
}

extern "C" void kernel_launch(void* const* d_in, const int* in_sizes, int n_in,
                              void* d_out, int out_size, void* d_ws, size_t ws_size,
                              hipStream_t stream) {
  const float* x = (const float*)d_in[0];
  const float* W = (const float*)d_in[1];
  const float* bias = (const float*)d_in[2];
  float* out = (float*)d_out;

  char* ws = (char*)d_ws;
  unsigned short* xt = (unsigned short*)(ws);
  unsigned short* wt = (unsigned short*)(ws + 16777216);
  unsigned short* qb = (unsigned short*)(ws + 23068672);
  unsigned short* kvb = (unsigned short*)(ws + 39845888);

  hipLaunchKernelGGL(cvt_both, dim3(5632), dim3(256), 0, stream, x, W, xt, wt);
  hipLaunchKernelGGL(qkv_gemm, dim3(64, 24), dim3(256), 0, stream, xt, wt, bias,
                     qb, kvb);
  hipLaunchKernelGGL(flash_attn, dim3(1024), dim3(128), 0, stream, qb, kvb, out);
}

// Round 10
// 204.246 us; speedup vs baseline: 2.0713x; 1.0361x over previous
//
#include <hip/hip_runtime.h>

// Attention: qkv = x @ W^T + b ; causal MHA ; B=4 T=2048 C=1024 H=16 D=64
// R10 (gemm + cvt only; flash frozen from R9):
//  - gemm: BK=32 double-buffer -> LDS 64KB->32KB -> 4-5 blocks/CU (R9 had 2,
//    OccupancyPercent 18%, the m132 pathology). Pre-tiled frag format already
//    indexes by ks, so BK=32 stages the 8 frags of one parity per step —
//    still contiguous 1KB DMAs, 2A+2B insts/wave/kt.
//  - cvt: inverted mapping — thread owns a 16B DST unit, gathers 8 floats
//    (2x float4 from one source row). Writes perfectly coalesced (R8/R9
//    forward-scatter had ~25% write efficiency).
// Flash (R9-verified): 2-wave blocks split t-rows, 2x16KB KV dbuf, 1 barrier
// per tile with tile-early DMA, fixed-m softmax via raw v_exp_f32, l via
// MFMA-ones, XCD-local head mapping, zero-conflict pre-tiled layouts.
// Workspace (70 MB): xt@0 tiled x bf16 | wt@16M tiled W | qb@22M q bf16
//   [bh][t][d] *0.125*log2e | kvb@38M KV tiles 16KB/tile.

typedef __attribute__((ext_vector_type(8))) short short8;
typedef __attribute__((ext_vector_type(4))) short s16x4;
typedef __attribute__((ext_vector_type(4))) float f32x4;

#define AS1 __attribute__((address_space(1)))
#define AS3 __attribute__((address_space(3)))

__device__ __forceinline__ unsigned short f2bf(float f) {
  unsigned int u = __float_as_uint(f);
  u += 0x7fffu + ((u >> 16) & 1u);
  return (unsigned short)(u >> 16);
}

__device__ __forceinline__ unsigned int pack_bf16(float lo, float hi) {
  return __builtin_amdgcn_perm(__float_as_uint(hi) + 0x8000u,
                               __float_as_uint(lo) + 0x8000u, 0x07060302u);
}

// async 16B/lane global->LDS; LDS dest = wave-uniform base + lane*16
__device__ __forceinline__ void async_copy16(const unsigned short* g, unsigned short* l) {
  const AS1 unsigned char* gp = (const AS1 unsigned char*)(unsigned long long)(uintptr_t)g;
  AS3 unsigned char* lp = (AS3 unsigned char*)(unsigned int)(uintptr_t)l;
  __builtin_amdgcn_global_load_lds((const AS1 void*)gp, (AS3 void*)lp, 16, 0, 0);
}

// ------------- fp32 -> bf16 convert, destination-ordered (gather) ----------
// Thread owns dst unit U (8 bf16 = 16B). Inverse of the frag-tile map:
//   u6=U&63, frag=(U>>6)&15, kt=(U>>10)&15, bt=U>>14
//   ks=frag&1, i=(frag>>1)&3, half=frag>>3
//   row = bt*128 + half*64 + i*16 + (u6&15); colf = kt*64 + ks*32 + (u6>>4)*8
__global__ __launch_bounds__(256) void cvt_both(const float* __restrict__ x,
                                                const float* __restrict__ W,
                                                unsigned short* __restrict__ xt,
                                                unsigned short* __restrict__ wt) {
  int U = blockIdx.x * 256 + threadIdx.x;  // 0 .. 1441791
  const float* in;
  unsigned short* out;
  if (U < 1048576) { in = x; out = xt; }
  else             { in = W; out = wt; U -= 1048576; }
  int u6 = U & 63, frag = (U >> 6) & 15, kt = (U >> 10) & 15, bt = U >> 14;
  int ks = frag & 1, i = (frag >> 1) & 3, half = frag >> 3;
  int row = bt * 128 + half * 64 + i * 16 + (u6 & 15);
  int colf = kt * 64 + ks * 32 + (u6 >> 4) * 8;
  const float4* p = (const float4*)(in + (size_t)row * 1024 + colf);
  float4 a = p[0], b = p[1];
  uint4 o;
  o.x = pack_bf16(a.x, a.y);
  o.y = pack_bf16(a.z, a.w);
  o.z = pack_bf16(b.x, b.y);
  o.w = pack_bf16(b.z, b.w);
  *(uint4*)(out + (size_t)U * 8) = o;
}

// ------------- QKV GEMM: BK=32 double-buffer, pre-tiled staging -------------
// 128x128 tile, 4 waves 2x2, wave 64x64 = 4x4 16x16x32 MFMA per kt32.
// LDS 2 x (8KB A + 8KB B) = 32KB -> 4-5 blocks/CU.
__global__ __launch_bounds__(256) void qkv_gemm(const unsigned short* __restrict__ xt,
                                                const unsigned short* __restrict__ wt,
                                                const float* __restrict__ bias,
                                                unsigned short* __restrict__ qb,
                                                unsigned short* __restrict__ kvb) {
  __shared__ unsigned short As[2][4096];
  __shared__ unsigned short Bs[2][4096];
  int tid = threadIdx.x;
  int wave = tid >> 6, lane = tid & 63;
  int q4 = lane >> 4, l16 = lane & 15;
  int bm = blockIdx.x, bn = blockIdx.y;

  f32x4 zero = {0.f, 0.f, 0.f, 0.f};
  f32x4 acc[4][4];
#pragma unroll
  for (int i = 0; i < 4; ++i)
#pragma unroll
    for (int j = 0; j < 4; ++j) acc[i][j] = zero;

  const unsigned short* Abase = xt + (size_t)bm * 16 * 8192;
  const unsigned short* Bbase = wt + (size_t)bn * 16 * 8192;

  // stage the 8 frags of parity ks for k-step kt32: frag = h*8 + i*2 + ks,
  // LDS slot fi = h*4 + i. Wave w covers fi = w*2 + {0,1} for A and B.
  auto stage = [&](int d, int kt32) {
    int kt64 = kt32 >> 1, ks = kt32 & 1;
    const unsigned short* ga = Abase + (size_t)kt64 * 8192;
    const unsigned short* gb = Bbase + (size_t)kt64 * 8192;
#pragma unroll
    for (int j = 0; j < 2; ++j) {
      int fi = wave * 2 + j;                       // 0..7
      int f = (fi >> 2) * 8 + (fi & 3) * 2 + ks;   // global frag index
      async_copy16(ga + f * 512 + lane * 8, &As[d][fi * 512]);
      async_copy16(gb + f * 512 + lane * 8, &Bs[d][fi * 512]);
    }
  };

  stage(0, 0);
  for (int kt = 0; kt < 32; ++kt) {
    __syncthreads();  // drains buf[kt&1]'s DMAs (issued a step ago)
    if (kt < 31) stage((kt + 1) & 1, kt + 1);
    const unsigned short* Ac = As[kt & 1];
    const unsigned short* Bc = Bs[kt & 1];
    short8 af[4], bf[4];
#pragma unroll
    for (int i = 0; i < 4; ++i)
      af[i] = *(const short8*)(Ac + ((wave & 1) * 4 + i) * 512 + lane * 8);
#pragma unroll
    for (int j = 0; j < 4; ++j)
      bf[j] = *(const short8*)(Bc + ((wave >> 1) * 4 + j) * 512 + lane * 8);
#pragma unroll
    for (int i = 0; i < 4; ++i)
#pragma unroll
      for (int j = 0; j < 4; ++j)
        acc[i][j] = __builtin_amdgcn_mfma_f32_16x16x32_bf16(af[i], bf[j], acc[i][j], 0, 0, 0);
  }

  // epilogue (R8/R9-verified): +bias; q *0.125*log2e; k,v -> pre-tiled kvb
  const float QSCALE = 0.18033688011112042f;
  int rowbase = bm * 128 + (wave & 1) * 64;
  int colbase = bn * 128 + (wave >> 1) * 64;
#pragma unroll
  for (int j = 0; j < 4; ++j) {
    int o = colbase + j * 16 + l16;
    float bv = bias[o];
#pragma unroll
    for (int i = 0; i < 4; ++i) {
      int r0 = rowbase + i * 16 + q4 * 4;
      int b = r0 >> 11, t0 = r0 & 2047;
      if (o < 1024) {
        int h = o >> 6, d = o & 63;
#pragma unroll
        for (int r = 0; r < 4; ++r)
          qb[((((size_t)b * 16 + h) * 2048 + t0 + r) << 6) + d] =
              f2bf((acc[i][j][r] + bv) * QSCALE);
      } else if (o < 2048) {
        int o2 = o - 1024;
        int h = o2 >> 6, dd = o2 & 63;
        int st = t0 >> 6, s6 = t0 & 63;
        int ns = s6 >> 4, l16p = s6 & 15;
        int ks = dd >> 5, q4p = (dd & 31) >> 3, jj = dd & 7;
        size_t base = ((size_t)(b * 16 + h) * 32 + st) * 8192 +
                      ((ns * 2 + ks) * 64 + q4p * 16 + l16p) * 8 + jj;
#pragma unroll
        for (int r = 0; r < 4; ++r)
          kvb[base + r * 8] = f2bf(acc[i][j][r] + bv);
      } else {
        int o3 = o - 2048;
        int h = o3 >> 6, dd = o3 & 63;
        int st = t0 >> 6, s6 = t0 & 63;
        int ns = s6 >> 4, q4p = (s6 >> 2) & 3;
        int p = dd >> 5, halfd = (dd >> 4) & 1, l16p = dd & 15;
        size_t base = ((size_t)(b * 16 + h) * 32 + st) * 8192 + 4096 +
                      ((ns * 2 + p) * 64 + q4p * 16 + l16p) * 8 + halfd * 4;
        ushort4 pk;
        pk.x = f2bf(acc[i][j][0] + bv);
        pk.y = f2bf(acc[i][j][1] + bv);
        pk.z = f2bf(acc[i][j][2] + bv);
        pk.w = f2bf(acc[i][j][3] + bv);
        *(ushort4*)(&kvb[base]) = pk;
      }
    }
  }
}

// ------------- Flash attention: XCD-local heads, raw exp2 (R9) --------------
__global__ __launch_bounds__(128, 4) void flash_attn(const unsigned short* __restrict__ qb,
                                                     const unsigned short* __restrict__ kvb,
                                                     float* __restrict__ out) {
  __shared__ unsigned short buf[2][8192];

  const int tid = threadIdx.x;
  const int wave = tid >> 6, lane = tid & 63;
  const int q4 = lane >> 4, l16 = lane & 15;
  const int n = blockIdx.x;
  const int bh = (n & 7) * 8 + ((n >> 3) & 7);
  const int bx = n >> 6;
  const int b = bh >> 4, h = bh & 15;

  const unsigned short* Qg = qb + (size_t)bh * (2048 * 64);
  const unsigned short* KVg = kvb + (size_t)bh * 32 * 8192;
  const s16x4 ones = {(short)0x3F80, (short)0x3F80, (short)0x3F80, (short)0x3F80};

  auto stage = [&](int d, int st) {
    const unsigned short* tp = KVg + (size_t)st * 8192;
#pragma unroll
    for (int i2 = 0; i2 < 8; ++i2) {
      int u = i2 * 128 + wave * 64;
      async_copy16(tp + (u + lane) * 8, &buf[d][u * 8]);
    }
  };

  for (int pass = 0; pass < 2; ++pass) {
    const int qt = pass ? 31 - bx : bx;
    const int t0w = qt * 64 + wave * 32;

    short8 qf[2][2];
#pragma unroll
    for (int mt = 0; mt < 2; ++mt)
#pragma unroll
      for (int ks = 0; ks < 2; ++ks)
        qf[mt][ks] = *(const short8*)(Qg + (size_t)(t0w + mt * 16 + l16) * 64 +
                                      ks * 32 + q4 * 8);

    f32x4 zero = {0.f, 0.f, 0.f, 0.f};
    f32x4 oT[2][4];
#pragma unroll
    for (int mt = 0; mt < 2; ++mt)
#pragma unroll
      for (int nd = 0; nd < 4; ++nd) oT[mt][nd] = zero;
    f32x4 l_acc[2] = {zero, zero};

    __syncthreads();  // prior pass's reads done before restaging buf0
    stage(0, 0);
    for (int st = 0; st <= qt; ++st) {
      __syncthreads();  // drains buf[st&1] DMAs (issued a tile ago)
      if (st < qt) stage((st + 1) & 1, st + 1);
      const unsigned short* cur = buf[st & 1];

      f32x4 sT[2][4];
#pragma unroll
      for (int ns = 0; ns < 4; ++ns) {
        short8 kf0 = *(const short8*)(cur + (ns * 2 + 0) * 512 + lane * 8);
        short8 kf1 = *(const short8*)(cur + (ns * 2 + 1) * 512 + lane * 8);
#pragma unroll
        for (int mt = 0; mt < 2; ++mt) {
          sT[mt][ns] = __builtin_amdgcn_mfma_f32_16x16x32_bf16(kf0, qf[mt][0], zero, 0, 0, 0);
          sT[mt][ns] = __builtin_amdgcn_mfma_f32_16x16x32_bf16(kf1, qf[mt][1], sT[mt][ns], 0, 0, 0);
        }
      }

      if (st == qt) {  // diagonal: mask s > t; exp2(-3e38) = 0
#pragma unroll
        for (int mt = 0; mt < 2; ++mt) {
          int tg = t0w + mt * 16 + l16;
#pragma unroll
          for (int ns = 0; ns < 4; ++ns) {
            int sgb = st * 64 + ns * 16 + q4 * 4;
#pragma unroll
            for (int r = 0; r < 4; ++r)
              if (sgb + r > tg) sT[mt][ns][r] = -3.0e38f;
          }
        }
      }

#pragma unroll
      for (int ns = 0; ns < 4; ++ns) {
        s16x4 pf[2];
#pragma unroll
        for (int mt = 0; mt < 2; ++mt) {
          union { unsigned int u[2]; s16x4 s4; } pu;
          pu.u[0] = pack_bf16(__builtin_amdgcn_exp2f(sT[mt][ns][0]),
                              __builtin_amdgcn_exp2f(sT[mt][ns][1]));
          pu.u[1] = pack_bf16(__builtin_amdgcn_exp2f(sT[mt][ns][2]),
                              __builtin_amdgcn_exp2f(sT[mt][ns][3]));
          pf[mt] = pu.s4;
        }
#pragma unroll
        for (int p = 0; p < 2; ++p) {
          short8 v8 = *(const short8*)(cur + 4096 + ((ns * 2 + p) * 64 + lane) * 8);
          s16x4 vlo = __builtin_shufflevector(v8, v8, 0, 1, 2, 3);
          s16x4 vhi = __builtin_shufflevector(v8, v8, 4, 5, 6, 7);
#pragma unroll
          for (int mt = 0; mt < 2; ++mt) {
            oT[mt][2 * p] = __builtin_amdgcn_mfma_f32_16x16x16bf16_1k(vlo, pf[mt], oT[mt][2 * p], 0, 0, 0);
            oT[mt][2 * p + 1] = __builtin_amdgcn_mfma_f32_16x16x16bf16_1k(vhi, pf[mt], oT[mt][2 * p + 1], 0, 0, 0);
          }
        }
#pragma unroll
        for (int mt = 0; mt < 2; ++mt)
          l_acc[mt] = __builtin_amdgcn_mfma_f32_16x16x16bf16_1k(ones, pf[mt], l_acc[mt], 0, 0, 0);
      }
    }

#pragma unroll
    for (int mt = 0; mt < 2; ++mt) {
      float inv = 1.0f / l_acc[mt][0];
      int t = t0w + mt * 16 + l16;
      float* op = out + (size_t)(b * 2048 + t) * 1024 + h * 64 + q4 * 4;
#pragma unroll
      for (int nd = 0; nd < 4; ++nd) {
        float4 o4 = {oT[mt][nd][0] * inv, oT[mt][nd][1] * inv,
                     oT[mt][nd][2] * inv, oT[mt][nd][3] * inv};
        *(float4*)(op + nd * 16) = o4;
      }
    }
  }
}

extern "C" void kernel_launch(void* const* d_in, const int* in_sizes, int n_in,
                              void* d_out, int out_size, void* d_ws, size_t ws_size,
                              hipStream_t stream) {
  const float* x = (const float*)d_in[0];
  const float* W = (const float*)d_in[1];
  const float* bias = (const float*)d_in[2];
  float* out = (float*)d_out;

  char* ws = (char*)d_ws;
  unsigned short* xt = (unsigned short*)(ws);
  unsigned short* wt = (unsigned short*)(ws + 16777216);
  unsigned short* qb = (unsigned short*)(ws + 23068672);
  unsigned short* kvb = (unsigned short*)(ws + 39845888);

  hipLaunchKernelGGL(cvt_both, dim3(5632), dim3(256), 0, stream, x, W, xt, wt);
  hipLaunchKernelGGL(qkv_gemm, dim3(64, 24), dim3(256), 0, stream, xt, wt, bias,
                     qb, kvb);
  hipLaunchKernelGGL(flash_attn, dim3(1024), dim3(128), 0, stream, qb, kvb, out);
}